// Round 3
// baseline (733.484 us; speedup 1.0000x reference)
//
#include <hip/hip_runtime.h>

typedef _Float16 half8  __attribute__((ext_vector_type(8)));
typedef float    f32x4  __attribute__((ext_vector_type(4)));
typedef unsigned short ushort8 __attribute__((ext_vector_type(8)));

__device__ __forceinline__ float clampf(float v, float lo, float hi){
    return fminf(fmaxf(v, lo), hi);
}
__device__ __forceinline__ float b2f(unsigned short u){
    unsigned int x = ((unsigned int)u) << 16;
    return __builtin_bit_cast(float, x);
}
__device__ __forceinline__ unsigned short f2b(float f){
    unsigned int u = __builtin_bit_cast(unsigned int, f);
    u += 0x7FFFu + ((u >> 16) & 1u);       // round-to-nearest-even
    return (unsigned short)(u >> 16);
}

// ---------------------------------------------------------------------------
// ws layout in _Float16 ELEMENT offsets (all tensors stored as integer-valued f16)
#define EW_WALL 0u                       // [1536][512] packed Wq/Wk/Wv rows
#define EW_WO   786432u                  // [512][512]
#define EW_AQ   1048576u                 // [8192][512] act for q-proj
#define EW_AK   (EW_AQ + 4194304u)
#define EW_AV   (EW_AK + 4194304u)
#define EW_Q    (EW_AV + 4194304u)       // [bh=32][s=2048][d=64]
#define EW_K    (EW_Q  + 4194304u)       // [bh][s][d]
#define EW_VT   (EW_K  + 4194304u)       // [bh][d=64][s=2048]  (V transposed)
#define EW_O    (EW_VT + 4194304u)       // [8192][512]
// total = 30,408,704 elements = 60,817,408 bytes

// ---------------------------------------------------------------------------
__global__ __launch_bounds__(256) void k_quant_w(
    const unsigned short* __restrict__ Wq, const unsigned short* __restrict__ Wk,
    const unsigned short* __restrict__ Wv, const unsigned short* __restrict__ Wo,
    _Float16* __restrict__ w_all, _Float16* __restrict__ wo16,
    const unsigned short* __restrict__ scu)
{
    int gid  = blockIdx.x * 256 + threadIdx.x;   // 131072 threads, 8 elems each
    int idx8 = gid * 8;
    int which = idx8 >> 18;                      // 262144 elems per matrix
    int rem   = idx8 & 262143;
    const unsigned short* W = (which==0)? Wq : (which==1)? Wk : (which==2)? Wv : Wo;
    float sw = b2f((which<3) ? scu[2 + 2*which] : scu[13]);
    ushort8 w = *(const ushort8*)(W + rem);
    half8 o;
    #pragma unroll
    for (int j=0;j<8;j++)
        o[j] = (_Float16)rintf(clampf(b2f(w[j])/sw, -128.f, 127.f));
    _Float16* dst = (which<3) ? (w_all + which*262144 + rem) : (wo16 + rem);
    *(half8*)dst = o;
}

// ---------------------------------------------------------------------------
__global__ __launch_bounds__(256) void k_quant_a(
    const unsigned short* __restrict__ hs,
    _Float16* __restrict__ aq, _Float16* __restrict__ ak, _Float16* __restrict__ av,
    const unsigned short* __restrict__ scu)
{
    int gid = blockIdx.x * 256 + threadIdx.x;    // 524288 threads, 8 elems each
    int i8 = gid * 8;
    float s0 = b2f(scu[0]), s1 = b2f(scu[1]), s3 = b2f(scu[3]), s5 = b2f(scu[5]);
    ushort8 h = *(const ushort8*)(hs + i8);
    half8 q, k, v;
    #pragma unroll
    for (int j=0;j<8;j++){
        float h1 = rintf(clampf(b2f(h[j])/s0, -128.f, 127.f)) * s0;  // fq(hs, s0)
        q[j] = (_Float16)rintf(clampf(h1/s1, -128.f, 127.f));
        k[j] = (_Float16)rintf(clampf(h1/s3, -128.f, 127.f));
        v[j] = (_Float16)rintf(clampf(h1/s5, -128.f, 127.f));
    }
    *(half8*)(aq+i8) = q;
    *(half8*)(ak+i8) = k;
    *(half8*)(av+i8) = v;
}

// ---------------------------------------------------------------------------
// QKV projection: M=8192, N=1536 (3 projections x 512), K=512. 128x128 tiles,
// 4 waves each doing 64x64 via verified mfma_f32_16x16x32_f16 (exact int math).
__global__ __launch_bounds__(256) void k_gemm_qkv(
    const _Float16* __restrict__ aq, const _Float16* __restrict__ ak,
    const _Float16* __restrict__ av, const _Float16* __restrict__ w_all,
    _Float16* __restrict__ q16, _Float16* __restrict__ k16, _Float16* __restrict__ vt16,
    const unsigned short* __restrict__ scu)
{
    __shared__ __align__(16) _Float16 At[128][64];
    __shared__ __align__(16) _Float16 Bt[128][64];
    int tid = threadIdx.x;
    int m0 = blockIdx.x*128, n0 = blockIdx.y*128;
    int proj = blockIdx.y >> 2;                  // 4 n-blocks per projection
    const _Float16* Ag = (proj==0)? aq : (proj==1)? ak : av;
    int w = tid>>6, lane = tid&63, l15 = lane&15, quad = lane>>4;
    int wm = w>>1, wn = w&1;
    f32x4 z = {0.f,0.f,0.f,0.f};
    f32x4 acc[4][4];
    #pragma unroll
    for (int i=0;i<4;i++)
      #pragma unroll
      for (int j=0;j<4;j++) acc[i][j] = z;

    for (int k0=0; k0<512; k0+=64){
        #pragma unroll
        for (int it=0; it<4; it++){
            int idx = it*256 + tid;              // 0..1023
            int row = idx>>3, col = (idx&7)*8;
            *(half8*)(&At[row][col]) = *(const half8*)(Ag    + (m0+row)*512 + k0 + col);
            *(half8*)(&Bt[row][col]) = *(const half8*)(w_all + (n0+row)*512 + k0 + col);
        }
        __syncthreads();
        half8 af[4][2], bf[4][2];
        #pragma unroll
        for (int mt=0; mt<4; mt++){
            af[mt][0] = *(const half8*)(&At[wm*64+mt*16+l15][quad*8]);
            af[mt][1] = *(const half8*)(&At[wm*64+mt*16+l15][32+quad*8]);
        }
        #pragma unroll
        for (int nt=0; nt<4; nt++){
            bf[nt][0] = *(const half8*)(&Bt[wn*64+nt*16+l15][quad*8]);
            bf[nt][1] = *(const half8*)(&Bt[wn*64+nt*16+l15][32+quad*8]);
        }
        #pragma unroll
        for (int mt=0; mt<4; mt++)
          #pragma unroll
          for (int nt=0; nt<4; nt++){
            acc[mt][nt] = __builtin_amdgcn_mfma_f32_16x16x32_f16(af[mt][0], bf[nt][0], acc[mt][nt], 0,0,0);
            acc[mt][nt] = __builtin_amdgcn_mfma_f32_16x16x32_f16(af[mt][1], bf[nt][1], acc[mt][nt], 0,0,0);
          }
        __syncthreads();
    }

    float ssc = b2f(scu[1+2*proj]) * b2f(scu[2+2*proj]);
    float qs  = b2f((proj==0)? scu[7] : (proj==1)? scu[8] : scu[11]);
    #pragma unroll
    for (int mt=0; mt<4; mt++){
      #pragma unroll
      for (int nt=0; nt<4; nt++){
        int n = n0 + wn*64 + nt*16 + l15;        // C/D col = lane&15 (verified)
        int nloc = n & 511;
        int h = nloc>>6, d = nloc&63;
        #pragma unroll
        for (int r=0;r<4;r++){
          int m = m0 + wm*64 + mt*16 + quad*4 + r;   // C/D row = quad*4+reg (verified)
          int b = m>>11, s = m&2047;
          int bh = b*8 + h;
          float val = acc[mt][nt][r] * ssc;          // exact integer * scale
          float qv = rintf(clampf(val/qs, -128.f, 127.f));
          if (proj==0)      q16 [(bh*2048 + s)*64 + d] = (_Float16)qv;
          else if (proj==1) k16 [(bh*2048 + s)*64 + d] = (_Float16)qv;
          else              vt16[(bh*64 + d)*2048 + s] = (_Float16)qv;   // transposed
        }
      }
    }
}

// ---------------------------------------------------------------------------
// Fused attention: block = (16 q-rows, bh). Wave w owns t in [w*512,(w+1)*512).
// Scores kept in registers (f32), exact softmax with cross-wave reduce, P
// quantized (sc9 then sc10), staged through barrier-protected LDS into
// A-fragment layout, PV via f16 MFMA, cross-wave reduce, quantize with sc12.
__global__ __launch_bounds__(256) void k_attn(
    const _Float16* __restrict__ q16, const _Float16* __restrict__ k16,
    const _Float16* __restrict__ vt16, _Float16* __restrict__ o16,
    const unsigned short* __restrict__ scu)
{
    __shared__ __align__(16) _Float16 p16[4][16][64];  // per-wave P staging
    __shared__ float red[4][16][64];                   // cross-wave PV reduce
    __shared__ float mred[4][16];
    __shared__ float lred[4][16];
    int tid = threadIdx.x;
    int w = tid>>6, lane = tid&63, l15 = lane&15, quad = lane>>4;
    int bh = blockIdx.y;
    int q0 = blockIdx.x * 16;
    float s9 = b2f(scu[9]), s10 = b2f(scu[10]);
    float alpha = b2f(scu[7]) * b2f(scu[8]) * 0.125f;    // DH^-0.5 = 0.125

    f32x4 z = {0.f,0.f,0.f,0.f};
    const _Float16* qr = q16 + (bh*2048 + q0 + l15)*64;
    half8 aq0 = *(const half8*)(qr + quad*8);
    half8 aq1 = *(const half8*)(qr + 32 + quad*8);

    // QK^T over this wave's 512-wide t range: 32 tiles of 16 t, K=64 in 2 subs
    f32x4 c[32];
    #pragma unroll
    for (int tt=0; tt<32; tt++){
        const _Float16* kr = k16 + (bh*2048 + w*512 + tt*16 + l15)*64;
        half8 bk0 = *(const half8*)(kr + quad*8);
        half8 bk1 = *(const half8*)(kr + 32 + quad*8);
        f32x4 s = __builtin_amdgcn_mfma_f32_16x16x32_f16(aq0, bk0, z, 0,0,0);
        c[tt]   = __builtin_amdgcn_mfma_f32_16x16x32_f16(aq1, bk1, s, 0,0,0);
    }

    // row max over t (cols l15 within quad, tiles, then waves)
    float mr[4] = {-3.4e38f, -3.4e38f, -3.4e38f, -3.4e38f};
    #pragma unroll
    for (int tt=0; tt<32; tt++)
      #pragma unroll
      for (int r=0;r<4;r++)
        mr[r] = fmaxf(mr[r], c[tt][r] * alpha);
    #pragma unroll
    for (int r=0;r<4;r++){
        #pragma unroll
        for (int d=1; d<16; d<<=1)
            mr[r] = fmaxf(mr[r], __shfl_xor(mr[r], d, 64));
    }
    if (l15 == 0){
        #pragma unroll
        for (int r=0;r<4;r++) mred[w][quad*4+r] = mr[r];
    }
    __syncthreads();
    float mm[4];
    #pragma unroll
    for (int r=0;r<4;r++){
        int row = quad*4+r;
        mm[r] = fmaxf(fmaxf(mred[0][row], mred[1][row]), fmaxf(mred[2][row], mred[3][row]));
    }
    // exp + row sum; cache e in the score registers
    float ls[4] = {0.f,0.f,0.f,0.f};
    #pragma unroll
    for (int tt=0; tt<32; tt++)
      #pragma unroll
      for (int r=0;r<4;r++){
        float e = expf(c[tt][r]*alpha - mm[r]);
        ls[r] += e;
        c[tt][r] = e;
      }
    #pragma unroll
    for (int r=0;r<4;r++){
        #pragma unroll
        for (int d=1; d<16; d<<=1)
            ls[r] += __shfl_xor(ls[r], d, 64);
    }
    if (l15 == 0){
        #pragma unroll
        for (int r=0;r<4;r++) lred[w][quad*4+r] = ls[r];
    }
    __syncthreads();
    float inv[4];
    #pragma unroll
    for (int r=0;r<4;r++){
        int row = quad*4+r;
        inv[r] = 1.0f / (lred[0][row] + lred[1][row] + lred[2][row] + lred[3][row]);
    }

    // P·V over this wave's t range, 64-t chunks, barrier-protected LDS transform
    f32x4 oacc[4];
    #pragma unroll
    for (int dt=0; dt<4; dt++) oacc[dt] = z;
    for (int ch=0; ch<8; ch++){
        #pragma unroll
        for (int j=0;j<4;j++){
            int tt = ch*4 + j;
            #pragma unroll
            for (int r=0;r<4;r++){
                float p  = c[tt][r] * inv[r];
                float p1 = rintf(clampf(p/s9, 0.f, 255.f)) * s9;   // fq(softmax, s9, 0, 255)
                float a  = rintf(clampf(p1/s10, -128.f, 127.f));   // fq(., s10)
                p16[w][quad*4+r][j*16+l15] = (_Float16)a;          // [qrow][tloc]
            }
        }
        __syncthreads();
        half8 ap0 = *(const half8*)(&p16[w][l15][quad*8]);
        half8 ap1 = *(const half8*)(&p16[w][l15][32+quad*8]);
        #pragma unroll
        for (int dt=0; dt<4; dt++){
            const _Float16* vr = vt16 + (bh*64 + dt*16 + l15)*2048 + w*512 + ch*64;
            half8 bv0 = *(const half8*)(vr + quad*8);
            half8 bv1 = *(const half8*)(vr + 32 + quad*8);
            oacc[dt] = __builtin_amdgcn_mfma_f32_16x16x32_f16(ap0, bv0, oacc[dt], 0,0,0);
            oacc[dt] = __builtin_amdgcn_mfma_f32_16x16x32_f16(ap1, bv1, oacc[dt], 0,0,0);
        }
        __syncthreads();
    }

    // cross-wave reduce (waves covered disjoint t ranges; sums are exact ints)
    #pragma unroll
    for (int dt=0; dt<4; dt++)
      #pragma unroll
      for (int r=0;r<4;r++)
        red[w][quad*4+r][dt*16+l15] = oacc[dt][r];
    __syncthreads();
    float s1011 = b2f(scu[10]) * b2f(scu[11]);
    float s12   = b2f(scu[12]);
    int e0 = tid*4;
    int row = e0>>6, col0 = e0&63;
    int b = bh>>3, h = bh&7;
    _Float16 ov[4];
    #pragma unroll
    for (int i=0;i<4;i++){
        int col = col0 + i;
        float sum = red[0][row][col] + red[1][row][col] + red[2][row][col] + red[3][row][col];
        float o = sum * s1011;
        ov[i] = (_Float16)rintf(clampf(o/s12, -128.f, 127.f));
    }
    _Float16* op = o16 + (b*2048 + q0 + row)*512 + h*64 + col0;
    op[0]=ov[0]; op[1]=ov[1]; op[2]=ov[2]; op[3]=ov[3];
}

// ---------------------------------------------------------------------------
// Output projection: M=8192, N=512, K=512, + bias, bf16 out.
__global__ __launch_bounds__(256) void k_gemm_out(
    const _Float16* __restrict__ o16, const _Float16* __restrict__ wo16,
    const unsigned short* __restrict__ bo, unsigned short* __restrict__ out,
    const unsigned short* __restrict__ scu)
{
    __shared__ __align__(16) _Float16 At[128][64];
    __shared__ __align__(16) _Float16 Bt[128][64];
    int tid = threadIdx.x;
    int m0 = blockIdx.x*128, n0 = blockIdx.y*128;
    int w = tid>>6, lane = tid&63, l15 = lane&15, quad = lane>>4;
    int wm = w>>1, wn = w&1;
    f32x4 z = {0.f,0.f,0.f,0.f};
    f32x4 acc[4][4];
    #pragma unroll
    for (int i=0;i<4;i++)
      #pragma unroll
      for (int j=0;j<4;j++) acc[i][j] = z;

    for (int k0=0; k0<512; k0+=64){
        #pragma unroll
        for (int it=0; it<4; it++){
            int idx = it*256 + tid;
            int row = idx>>3, col = (idx&7)*8;
            *(half8*)(&At[row][col]) = *(const half8*)(o16  + (m0+row)*512 + k0 + col);
            *(half8*)(&Bt[row][col]) = *(const half8*)(wo16 + (n0+row)*512 + k0 + col);
        }
        __syncthreads();
        half8 af[4][2], bf[4][2];
        #pragma unroll
        for (int mt=0; mt<4; mt++){
            af[mt][0] = *(const half8*)(&At[wm*64+mt*16+l15][quad*8]);
            af[mt][1] = *(const half8*)(&At[wm*64+mt*16+l15][32+quad*8]);
        }
        #pragma unroll
        for (int nt=0; nt<4; nt++){
            bf[nt][0] = *(const half8*)(&Bt[wn*64+nt*16+l15][quad*8]);
            bf[nt][1] = *(const half8*)(&Bt[wn*64+nt*16+l15][32+quad*8]);
        }
        #pragma unroll
        for (int mt=0; mt<4; mt++)
          #pragma unroll
          for (int nt=0; nt<4; nt++){
            acc[mt][nt] = __builtin_amdgcn_mfma_f32_16x16x32_f16(af[mt][0], bf[nt][0], acc[mt][nt], 0,0,0);
            acc[mt][nt] = __builtin_amdgcn_mfma_f32_16x16x32_f16(af[mt][1], bf[nt][1], acc[mt][nt], 0,0,0);
          }
        __syncthreads();
    }

    float ssc = b2f(scu[12]) * b2f(scu[13]);
    #pragma unroll
    for (int mt=0; mt<4; mt++){
      #pragma unroll
      for (int nt=0; nt<4; nt++){
        int n = n0 + wn*64 + nt*16 + l15;
        float bn = b2f(bo[n]);
        #pragma unroll
        for (int r=0;r<4;r++){
          int m = m0 + wm*64 + mt*16 + quad*4 + r;
          out[m*512 + n] = f2b(acc[mt][nt][r]*ssc + bn);
        }
      }
    }
}

// ---------------------------------------------------------------------------
extern "C" void kernel_launch(void* const* d_in, const int* in_sizes, int n_in,
                              void* d_out, int out_size, void* d_ws, size_t ws_size,
                              hipStream_t stream)
{
    const unsigned short* hs = (const unsigned short*)d_in[0];
    const unsigned short* Wq = (const unsigned short*)d_in[1];
    const unsigned short* Wk = (const unsigned short*)d_in[2];
    const unsigned short* Wv = (const unsigned short*)d_in[3];
    const unsigned short* Wo = (const unsigned short*)d_in[4];
    const unsigned short* bo = (const unsigned short*)d_in[5];
    const unsigned short* sc = (const unsigned short*)d_in[6];
    unsigned short* out = (unsigned short*)d_out;

    _Float16* wsh   = (_Float16*)d_ws;
    _Float16* w_all = wsh + EW_WALL;
    _Float16* wo16  = wsh + EW_WO;
    _Float16* a_q   = wsh + EW_AQ;
    _Float16* a_k   = wsh + EW_AK;
    _Float16* a_v   = wsh + EW_AV;
    _Float16* q16   = wsh + EW_Q;
    _Float16* k16   = wsh + EW_K;
    _Float16* vt16  = wsh + EW_VT;
    _Float16* o16   = wsh + EW_O;

    k_quant_w<<<512,  256, 0, stream>>>(Wq, Wk, Wv, Wo, w_all, wo16, sc);
    k_quant_a<<<2048, 256, 0, stream>>>(hs, a_q, a_k, a_v, sc);
    k_gemm_qkv<<<dim3(64,12), 256, 0, stream>>>(a_q, a_k, a_v, w_all, q16, k16, vt16, sc);
    k_attn<<<dim3(128,32), 256, 0, stream>>>(q16, k16, vt16, o16, sc);
    k_gemm_out<<<dim3(64,4), 256, 0, stream>>>(o16, wo16, bo, out, sc);
}

// Round 4
// 546.337 us; speedup vs baseline: 1.3425x; 1.3425x over previous
//
#include <hip/hip_runtime.h>

typedef _Float16 half8  __attribute__((ext_vector_type(8)));
typedef float    f32x4  __attribute__((ext_vector_type(4)));
typedef unsigned short ushort8 __attribute__((ext_vector_type(8)));

__device__ __forceinline__ float clampf(float v, float lo, float hi){
    return fminf(fmaxf(v, lo), hi);
}
__device__ __forceinline__ float b2f(unsigned short u){
    unsigned int x = ((unsigned int)u) << 16;
    return __builtin_bit_cast(float, x);
}
__device__ __forceinline__ unsigned short f2b(float f){
    unsigned int u = __builtin_bit_cast(unsigned int, f);
    u += 0x7FFFu + ((u >> 16) & 1u);       // round-to-nearest-even
    return (unsigned short)(u >> 16);
}

// ---------------------------------------------------------------------------
// ws layout in _Float16 ELEMENT offsets (all tensors stored as integer-valued f16)
#define EW_WALL 0u                       // [1536][512] packed Wq/Wk/Wv rows
#define EW_WO   786432u                  // [512][512]
#define EW_AQ   1048576u                 // [8192][512] act for q-proj
#define EW_AK   (EW_AQ + 4194304u)
#define EW_AV   (EW_AK + 4194304u)
#define EW_Q    (EW_AV + 4194304u)       // [bh=32][s=2048][d=64]
#define EW_K    (EW_Q  + 4194304u)       // [bh][s][d]
#define EW_VT   (EW_K  + 4194304u)       // [bh][d=64][s=2048]  (V transposed)
#define EW_O    (EW_VT + 4194304u)       // [8192][512]
// total = 30,408,704 elements = 60,817,408 bytes

// ---------------------------------------------------------------------------
__global__ __launch_bounds__(256) void k_quant_w(
    const unsigned short* __restrict__ Wq, const unsigned short* __restrict__ Wk,
    const unsigned short* __restrict__ Wv, const unsigned short* __restrict__ Wo,
    _Float16* __restrict__ w_all, _Float16* __restrict__ wo16,
    const unsigned short* __restrict__ scu)
{
    int gid  = blockIdx.x * 256 + threadIdx.x;   // 131072 threads, 8 elems each
    int idx8 = gid * 8;
    int which = idx8 >> 18;                      // 262144 elems per matrix
    int rem   = idx8 & 262143;
    const unsigned short* W = (which==0)? Wq : (which==1)? Wk : (which==2)? Wv : Wo;
    float sw = b2f((which<3) ? scu[2 + 2*which] : scu[13]);
    ushort8 w = *(const ushort8*)(W + rem);
    half8 o;
    #pragma unroll
    for (int j=0;j<8;j++)
        o[j] = (_Float16)rintf(clampf(b2f(w[j])/sw, -128.f, 127.f));
    _Float16* dst = (which<3) ? (w_all + which*262144 + rem) : (wo16 + rem);
    *(half8*)dst = o;
}

// ---------------------------------------------------------------------------
__global__ __launch_bounds__(256) void k_quant_a(
    const unsigned short* __restrict__ hs,
    _Float16* __restrict__ aq, _Float16* __restrict__ ak, _Float16* __restrict__ av,
    const unsigned short* __restrict__ scu)
{
    int gid = blockIdx.x * 256 + threadIdx.x;    // 524288 threads, 8 elems each
    int i8 = gid * 8;
    float s0 = b2f(scu[0]), s1 = b2f(scu[1]), s3 = b2f(scu[3]), s5 = b2f(scu[5]);
    ushort8 h = *(const ushort8*)(hs + i8);
    half8 q, k, v;
    #pragma unroll
    for (int j=0;j<8;j++){
        float h1 = rintf(clampf(b2f(h[j])/s0, -128.f, 127.f)) * s0;  // fq(hs, s0)
        q[j] = (_Float16)rintf(clampf(h1/s1, -128.f, 127.f));
        k[j] = (_Float16)rintf(clampf(h1/s3, -128.f, 127.f));
        v[j] = (_Float16)rintf(clampf(h1/s5, -128.f, 127.f));
    }
    *(half8*)(aq+i8) = q;
    *(half8*)(ak+i8) = k;
    *(half8*)(av+i8) = v;
}

// ---------------------------------------------------------------------------
// QKV projection: M=8192, N=1536 (3 projections x 512), K=512. 128x128 tiles,
// 4 waves each doing 64x64 via verified mfma_f32_16x16x32_f16 (exact int math).
__global__ __launch_bounds__(256) void k_gemm_qkv(
    const _Float16* __restrict__ aq, const _Float16* __restrict__ ak,
    const _Float16* __restrict__ av, const _Float16* __restrict__ w_all,
    _Float16* __restrict__ q16, _Float16* __restrict__ k16, _Float16* __restrict__ vt16,
    const unsigned short* __restrict__ scu)
{
    __shared__ __align__(16) _Float16 At[128][64];
    __shared__ __align__(16) _Float16 Bt[128][64];
    int tid = threadIdx.x;
    int m0 = blockIdx.x*128, n0 = blockIdx.y*128;
    int proj = blockIdx.y >> 2;                  // 4 n-blocks per projection
    const _Float16* Ag = (proj==0)? aq : (proj==1)? ak : av;
    int w = tid>>6, lane = tid&63, l15 = lane&15, quad = lane>>4;
    int wm = w>>1, wn = w&1;
    f32x4 z = {0.f,0.f,0.f,0.f};
    f32x4 acc[4][4];
    #pragma unroll
    for (int i=0;i<4;i++)
      #pragma unroll
      for (int j=0;j<4;j++) acc[i][j] = z;

    for (int k0=0; k0<512; k0+=64){
        #pragma unroll
        for (int it=0; it<4; it++){
            int idx = it*256 + tid;              // 0..1023
            int row = idx>>3, col = (idx&7)*8;
            *(half8*)(&At[row][col]) = *(const half8*)(Ag    + (m0+row)*512 + k0 + col);
            *(half8*)(&Bt[row][col]) = *(const half8*)(w_all + (n0+row)*512 + k0 + col);
        }
        __syncthreads();
        half8 af[4][2], bf[4][2];
        #pragma unroll
        for (int mt=0; mt<4; mt++){
            af[mt][0] = *(const half8*)(&At[wm*64+mt*16+l15][quad*8]);
            af[mt][1] = *(const half8*)(&At[wm*64+mt*16+l15][32+quad*8]);
        }
        #pragma unroll
        for (int nt=0; nt<4; nt++){
            bf[nt][0] = *(const half8*)(&Bt[wn*64+nt*16+l15][quad*8]);
            bf[nt][1] = *(const half8*)(&Bt[wn*64+nt*16+l15][32+quad*8]);
        }
        #pragma unroll
        for (int mt=0; mt<4; mt++)
          #pragma unroll
          for (int nt=0; nt<4; nt++){
            acc[mt][nt] = __builtin_amdgcn_mfma_f32_16x16x32_f16(af[mt][0], bf[nt][0], acc[mt][nt], 0,0,0);
            acc[mt][nt] = __builtin_amdgcn_mfma_f32_16x16x32_f16(af[mt][1], bf[nt][1], acc[mt][nt], 0,0,0);
          }
        __syncthreads();
    }

    float ssc = b2f(scu[1+2*proj]) * b2f(scu[2+2*proj]);
    float qs  = b2f((proj==0)? scu[7] : (proj==1)? scu[8] : scu[11]);
    #pragma unroll
    for (int mt=0; mt<4; mt++){
      #pragma unroll
      for (int nt=0; nt<4; nt++){
        int n = n0 + wn*64 + nt*16 + l15;        // C/D col = lane&15 (verified)
        int nloc = n & 511;
        int h = nloc>>6, d = nloc&63;
        #pragma unroll
        for (int r=0;r<4;r++){
          int m = m0 + wm*64 + mt*16 + quad*4 + r;   // C/D row = quad*4+reg (verified)
          int b = m>>11, s = m&2047;
          int bh = b*8 + h;
          float val = acc[mt][nt][r] * ssc;          // exact integer * scale
          float qv = rintf(clampf(val/qs, -128.f, 127.f));
          if (proj==0)      q16 [(bh*2048 + s)*64 + d] = (_Float16)qv;
          else if (proj==1) k16 [(bh*2048 + s)*64 + d] = (_Float16)qv;
          else              vt16[(bh*64 + d)*2048 + s] = (_Float16)qv;   // transposed
        }
      }
    }
}

// ---------------------------------------------------------------------------
// Fused attention: block = (16 q-rows, bh). Wave w owns t in [w*512,(w+1)*512).
// Scores kept in registers (f32), exact softmax with cross-wave reduce, P
// quantized (sc9 then sc10), staged through barrier-protected LDS into
// A-fragment layout, PV via f16 MFMA, cross-wave reduce, quantize with sc12.
// __launch_bounds__(256,2): 2 blocks/CU -> 256-VGPR budget so the 128-reg
// score cache does NOT spill to scratch (R3: 144 VGPR cap caused ~1GB spill).
__global__ __launch_bounds__(256, 2) void k_attn(
    const _Float16* __restrict__ q16, const _Float16* __restrict__ k16,
    const _Float16* __restrict__ vt16, _Float16* __restrict__ o16,
    const unsigned short* __restrict__ scu)
{
    __shared__ __align__(16) _Float16 p16[4][16][64];  // per-wave P staging
    __shared__ float red[4][16][64];                   // cross-wave PV reduce
    __shared__ float mred[4][16];
    __shared__ float lred[4][16];
    int tid = threadIdx.x;
    int w = tid>>6, lane = tid&63, l15 = lane&15, quad = lane>>4;
    int bh = blockIdx.y;
    int q0 = blockIdx.x * 16;
    float s9 = b2f(scu[9]), s10 = b2f(scu[10]);
    float alpha = b2f(scu[7]) * b2f(scu[8]) * 0.125f;    // DH^-0.5 = 0.125

    f32x4 z = {0.f,0.f,0.f,0.f};
    const _Float16* qr = q16 + (bh*2048 + q0 + l15)*64;
    half8 aq0 = *(const half8*)(qr + quad*8);
    half8 aq1 = *(const half8*)(qr + 32 + quad*8);

    // QK^T over this wave's 512-wide t range: 32 tiles of 16 t, K=64 in 2 subs
    f32x4 c[32];
    #pragma unroll
    for (int tt=0; tt<32; tt++){
        const _Float16* kr = k16 + (bh*2048 + w*512 + tt*16 + l15)*64;
        half8 bk0 = *(const half8*)(kr + quad*8);
        half8 bk1 = *(const half8*)(kr + 32 + quad*8);
        f32x4 s = __builtin_amdgcn_mfma_f32_16x16x32_f16(aq0, bk0, z, 0,0,0);
        c[tt]   = __builtin_amdgcn_mfma_f32_16x16x32_f16(aq1, bk1, s, 0,0,0);
    }

    // row max over t (cols l15 within quad, tiles, then waves)
    float mr[4] = {-3.4e38f, -3.4e38f, -3.4e38f, -3.4e38f};
    #pragma unroll
    for (int tt=0; tt<32; tt++)
      #pragma unroll
      for (int r=0;r<4;r++)
        mr[r] = fmaxf(mr[r], c[tt][r] * alpha);
    #pragma unroll
    for (int r=0;r<4;r++){
        #pragma unroll
        for (int d=1; d<16; d<<=1)
            mr[r] = fmaxf(mr[r], __shfl_xor(mr[r], d, 64));
    }
    if (l15 == 0){
        #pragma unroll
        for (int r=0;r<4;r++) mred[w][quad*4+r] = mr[r];
    }
    __syncthreads();
    float mm[4];
    #pragma unroll
    for (int r=0;r<4;r++){
        int row = quad*4+r;
        mm[r] = fmaxf(fmaxf(mred[0][row], mred[1][row]), fmaxf(mred[2][row], mred[3][row]));
    }
    // exp + row sum; cache e in the score registers
    float ls[4] = {0.f,0.f,0.f,0.f};
    #pragma unroll
    for (int tt=0; tt<32; tt++)
      #pragma unroll
      for (int r=0;r<4;r++){
        float e = expf(c[tt][r]*alpha - mm[r]);
        ls[r] += e;
        c[tt][r] = e;
      }
    #pragma unroll
    for (int r=0;r<4;r++){
        #pragma unroll
        for (int d=1; d<16; d<<=1)
            ls[r] += __shfl_xor(ls[r], d, 64);
    }
    if (l15 == 0){
        #pragma unroll
        for (int r=0;r<4;r++) lred[w][quad*4+r] = ls[r];
    }
    __syncthreads();
    float inv[4];
    #pragma unroll
    for (int r=0;r<4;r++){
        int row = quad*4+r;
        inv[r] = 1.0f / (lred[0][row] + lred[1][row] + lred[2][row] + lred[3][row]);
    }

    // P·V over this wave's t range, 64-t chunks, barrier-protected LDS transform
    f32x4 oacc[4];
    #pragma unroll
    for (int dt=0; dt<4; dt++) oacc[dt] = z;
    for (int ch=0; ch<8; ch++){
        #pragma unroll
        for (int j=0;j<4;j++){
            int tt = ch*4 + j;
            #pragma unroll
            for (int r=0;r<4;r++){
                float p  = c[tt][r] * inv[r];
                float p1 = rintf(clampf(p/s9, 0.f, 255.f)) * s9;   // fq(softmax, s9, 0, 255)
                float a  = rintf(clampf(p1/s10, -128.f, 127.f));   // fq(., s10)
                p16[w][quad*4+r][j*16+l15] = (_Float16)a;          // [qrow][tloc]
            }
        }
        __syncthreads();
        half8 ap0 = *(const half8*)(&p16[w][l15][quad*8]);
        half8 ap1 = *(const half8*)(&p16[w][l15][32+quad*8]);
        #pragma unroll
        for (int dt=0; dt<4; dt++){
            const _Float16* vr = vt16 + (bh*64 + dt*16 + l15)*2048 + w*512 + ch*64;
            half8 bv0 = *(const half8*)(vr + quad*8);
            half8 bv1 = *(const half8*)(vr + 32 + quad*8);
            oacc[dt] = __builtin_amdgcn_mfma_f32_16x16x32_f16(ap0, bv0, oacc[dt], 0,0,0);
            oacc[dt] = __builtin_amdgcn_mfma_f32_16x16x32_f16(ap1, bv1, oacc[dt], 0,0,0);
        }
        __syncthreads();
    }

    // cross-wave reduce (waves covered disjoint t ranges; sums are exact ints)
    #pragma unroll
    for (int dt=0; dt<4; dt++)
      #pragma unroll
      for (int r=0;r<4;r++)
        red[w][quad*4+r][dt*16+l15] = oacc[dt][r];
    __syncthreads();
    float s1011 = b2f(scu[10]) * b2f(scu[11]);
    float s12   = b2f(scu[12]);
    int e0 = tid*4;
    int row = e0>>6, col0 = e0&63;
    int b = bh>>3, h = bh&7;
    _Float16 ov[4];
    #pragma unroll
    for (int i=0;i<4;i++){
        int col = col0 + i;
        float sum = red[0][row][col] + red[1][row][col] + red[2][row][col] + red[3][row][col];
        float o = sum * s1011;
        ov[i] = (_Float16)rintf(clampf(o/s12, -128.f, 127.f));
    }
    _Float16* op = o16 + (b*2048 + q0 + row)*512 + h*64 + col0;
    op[0]=ov[0]; op[1]=ov[1]; op[2]=ov[2]; op[3]=ov[3];
}

// ---------------------------------------------------------------------------
// Output projection: M=8192, N=512, K=512, + bias, bf16 out.
__global__ __launch_bounds__(256) void k_gemm_out(
    const _Float16* __restrict__ o16, const _Float16* __restrict__ wo16,
    const unsigned short* __restrict__ bo, unsigned short* __restrict__ out,
    const unsigned short* __restrict__ scu)
{
    __shared__ __align__(16) _Float16 At[128][64];
    __shared__ __align__(16) _Float16 Bt[128][64];
    int tid = threadIdx.x;
    int m0 = blockIdx.x*128, n0 = blockIdx.y*128;
    int w = tid>>6, lane = tid&63, l15 = lane&15, quad = lane>>4;
    int wm = w>>1, wn = w&1;
    f32x4 z = {0.f,0.f,0.f,0.f};
    f32x4 acc[4][4];
    #pragma unroll
    for (int i=0;i<4;i++)
      #pragma unroll
      for (int j=0;j<4;j++) acc[i][j] = z;

    for (int k0=0; k0<512; k0+=64){
        #pragma unroll
        for (int it=0; it<4; it++){
            int idx = it*256 + tid;
            int row = idx>>3, col = (idx&7)*8;
            *(half8*)(&At[row][col]) = *(const half8*)(o16  + (m0+row)*512 + k0 + col);
            *(half8*)(&Bt[row][col]) = *(const half8*)(wo16 + (n0+row)*512 + k0 + col);
        }
        __syncthreads();
        half8 af[4][2], bf[4][2];
        #pragma unroll
        for (int mt=0; mt<4; mt++){
            af[mt][0] = *(const half8*)(&At[wm*64+mt*16+l15][quad*8]);
            af[mt][1] = *(const half8*)(&At[wm*64+mt*16+l15][32+quad*8]);
        }
        #pragma unroll
        for (int nt=0; nt<4; nt++){
            bf[nt][0] = *(const half8*)(&Bt[wn*64+nt*16+l15][quad*8]);
            bf[nt][1] = *(const half8*)(&Bt[wn*64+nt*16+l15][32+quad*8]);
        }
        #pragma unroll
        for (int mt=0; mt<4; mt++)
          #pragma unroll
          for (int nt=0; nt<4; nt++){
            acc[mt][nt] = __builtin_amdgcn_mfma_f32_16x16x32_f16(af[mt][0], bf[nt][0], acc[mt][nt], 0,0,0);
            acc[mt][nt] = __builtin_amdgcn_mfma_f32_16x16x32_f16(af[mt][1], bf[nt][1], acc[mt][nt], 0,0,0);
          }
        __syncthreads();
    }

    float ssc = b2f(scu[12]) * b2f(scu[13]);
    #pragma unroll
    for (int mt=0; mt<4; mt++){
      #pragma unroll
      for (int nt=0; nt<4; nt++){
        int n = n0 + wn*64 + nt*16 + l15;
        float bn = b2f(bo[n]);
        #pragma unroll
        for (int r=0;r<4;r++){
          int m = m0 + wm*64 + mt*16 + quad*4 + r;
          out[m*512 + n] = f2b(acc[mt][nt][r]*ssc + bn);
        }
      }
    }
}

// ---------------------------------------------------------------------------
extern "C" void kernel_launch(void* const* d_in, const int* in_sizes, int n_in,
                              void* d_out, int out_size, void* d_ws, size_t ws_size,
                              hipStream_t stream)
{
    const unsigned short* hs = (const unsigned short*)d_in[0];
    const unsigned short* Wq = (const unsigned short*)d_in[1];
    const unsigned short* Wk = (const unsigned short*)d_in[2];
    const unsigned short* Wv = (const unsigned short*)d_in[3];
    const unsigned short* Wo = (const unsigned short*)d_in[4];
    const unsigned short* bo = (const unsigned short*)d_in[5];
    const unsigned short* sc = (const unsigned short*)d_in[6];
    unsigned short* out = (unsigned short*)d_out;

    _Float16* wsh   = (_Float16*)d_ws;
    _Float16* w_all = wsh + EW_WALL;
    _Float16* wo16  = wsh + EW_WO;
    _Float16* a_q   = wsh + EW_AQ;
    _Float16* a_k   = wsh + EW_AK;
    _Float16* a_v   = wsh + EW_AV;
    _Float16* q16   = wsh + EW_Q;
    _Float16* k16   = wsh + EW_K;
    _Float16* vt16  = wsh + EW_VT;
    _Float16* o16   = wsh + EW_O;

    k_quant_w<<<512,  256, 0, stream>>>(Wq, Wk, Wv, Wo, w_all, wo16, sc);
    k_quant_a<<<2048, 256, 0, stream>>>(hs, a_q, a_k, a_v, sc);
    k_gemm_qkv<<<dim3(64,12), 256, 0, stream>>>(a_q, a_k, a_v, w_all, q16, k16, vt16, sc);
    k_attn<<<dim3(128,32), 256, 0, stream>>>(q16, k16, vt16, o16, sc);
    k_gemm_out<<<dim3(64,4), 256, 0, stream>>>(o16, wo16, bo, out, sc);
}

// Round 5
// 456.487 us; speedup vs baseline: 1.6068x; 1.1968x over previous
//
#include <hip/hip_runtime.h>

typedef _Float16 half8  __attribute__((ext_vector_type(8)));
typedef float    f32x4  __attribute__((ext_vector_type(4)));
typedef unsigned short ushort8 __attribute__((ext_vector_type(8)));

__device__ __forceinline__ float clampf(float v, float lo, float hi){
    return fminf(fmaxf(v, lo), hi);
}
__device__ __forceinline__ float b2f(unsigned short u){
    unsigned int x = ((unsigned int)u) << 16;
    return __builtin_bit_cast(float, x);
}
__device__ __forceinline__ unsigned short f2b(float f){
    unsigned int u = __builtin_bit_cast(unsigned int, f);
    u += 0x7FFFu + ((u >> 16) & 1u);       // round-to-nearest-even
    return (unsigned short)(u >> 16);
}

// ---------------------------------------------------------------------------
// ws layout in _Float16 ELEMENT offsets (all tensors stored as integer-valued f16)
#define EW_WALL 0u                       // [1536][512] packed Wq/Wk/Wv rows
#define EW_WO   786432u                  // [512][512]
#define EW_AQ   1048576u                 // [8192][512] act for q-proj
#define EW_AK   (EW_AQ + 4194304u)
#define EW_AV   (EW_AK + 4194304u)
#define EW_Q    (EW_AV + 4194304u)       // [bh=32][s=2048][d=64]
#define EW_K    (EW_Q  + 4194304u)       // [bh][s][d]
#define EW_VT   (EW_K  + 4194304u)       // [bh][d=64][s=2048]  (V transposed)
#define EW_O    (EW_VT + 4194304u)       // [8192][512]
// total = 30,408,704 elements = 60,817,408 bytes

// ---------------------------------------------------------------------------
__global__ __launch_bounds__(256) void k_quant_w(
    const unsigned short* __restrict__ Wq, const unsigned short* __restrict__ Wk,
    const unsigned short* __restrict__ Wv, const unsigned short* __restrict__ Wo,
    _Float16* __restrict__ w_all, _Float16* __restrict__ wo16,
    const unsigned short* __restrict__ scu)
{
    int gid  = blockIdx.x * 256 + threadIdx.x;   // 131072 threads, 8 elems each
    int idx8 = gid * 8;
    int which = idx8 >> 18;                      // 262144 elems per matrix
    int rem   = idx8 & 262143;
    const unsigned short* W = (which==0)? Wq : (which==1)? Wk : (which==2)? Wv : Wo;
    float sw = b2f((which<3) ? scu[2 + 2*which] : scu[13]);
    ushort8 w = *(const ushort8*)(W + rem);
    half8 o;
    #pragma unroll
    for (int j=0;j<8;j++)
        o[j] = (_Float16)rintf(clampf(b2f(w[j])/sw, -128.f, 127.f));
    _Float16* dst = (which<3) ? (w_all + which*262144 + rem) : (wo16 + rem);
    *(half8*)dst = o;
}

// ---------------------------------------------------------------------------
__global__ __launch_bounds__(256) void k_quant_a(
    const unsigned short* __restrict__ hs,
    _Float16* __restrict__ aq, _Float16* __restrict__ ak, _Float16* __restrict__ av,
    const unsigned short* __restrict__ scu)
{
    int gid = blockIdx.x * 256 + threadIdx.x;    // 524288 threads, 8 elems each
    int i8 = gid * 8;
    float s0 = b2f(scu[0]), s1 = b2f(scu[1]), s3 = b2f(scu[3]), s5 = b2f(scu[5]);
    ushort8 h = *(const ushort8*)(hs + i8);
    half8 q, k, v;
    #pragma unroll
    for (int j=0;j<8;j++){
        float h1 = rintf(clampf(b2f(h[j])/s0, -128.f, 127.f)) * s0;  // fq(hs, s0)
        q[j] = (_Float16)rintf(clampf(h1/s1, -128.f, 127.f));
        k[j] = (_Float16)rintf(clampf(h1/s3, -128.f, 127.f));
        v[j] = (_Float16)rintf(clampf(h1/s5, -128.f, 127.f));
    }
    *(half8*)(aq+i8) = q;
    *(half8*)(ak+i8) = k;
    *(half8*)(av+i8) = v;
}

// ---------------------------------------------------------------------------
// QKV projection: M=8192, N=1536 (3 projections x 512), K=512. 128x128 tiles,
// 4 waves each doing 64x64 via verified mfma_f32_16x16x32_f16 (exact int math).
__global__ __launch_bounds__(256) void k_gemm_qkv(
    const _Float16* __restrict__ aq, const _Float16* __restrict__ ak,
    const _Float16* __restrict__ av, const _Float16* __restrict__ w_all,
    _Float16* __restrict__ q16, _Float16* __restrict__ k16, _Float16* __restrict__ vt16,
    const unsigned short* __restrict__ scu)
{
    __shared__ __align__(16) _Float16 At[128][64];
    __shared__ __align__(16) _Float16 Bt[128][64];
    int tid = threadIdx.x;
    int m0 = blockIdx.x*128, n0 = blockIdx.y*128;
    int proj = blockIdx.y >> 2;                  // 4 n-blocks per projection
    const _Float16* Ag = (proj==0)? aq : (proj==1)? ak : av;
    int w = tid>>6, lane = tid&63, l15 = lane&15, quad = lane>>4;
    int wm = w>>1, wn = w&1;
    f32x4 z = {0.f,0.f,0.f,0.f};
    f32x4 acc[4][4];
    #pragma unroll
    for (int i=0;i<4;i++)
      #pragma unroll
      for (int j=0;j<4;j++) acc[i][j] = z;

    for (int k0=0; k0<512; k0+=64){
        #pragma unroll
        for (int it=0; it<4; it++){
            int idx = it*256 + tid;              // 0..1023
            int row = idx>>3, col = (idx&7)*8;
            *(half8*)(&At[row][col]) = *(const half8*)(Ag    + (m0+row)*512 + k0 + col);
            *(half8*)(&Bt[row][col]) = *(const half8*)(w_all + (n0+row)*512 + k0 + col);
        }
        __syncthreads();
        half8 af[4][2], bf[4][2];
        #pragma unroll
        for (int mt=0; mt<4; mt++){
            af[mt][0] = *(const half8*)(&At[wm*64+mt*16+l15][quad*8]);
            af[mt][1] = *(const half8*)(&At[wm*64+mt*16+l15][32+quad*8]);
        }
        #pragma unroll
        for (int nt=0; nt<4; nt++){
            bf[nt][0] = *(const half8*)(&Bt[wn*64+nt*16+l15][quad*8]);
            bf[nt][1] = *(const half8*)(&Bt[wn*64+nt*16+l15][32+quad*8]);
        }
        #pragma unroll
        for (int mt=0; mt<4; mt++)
          #pragma unroll
          for (int nt=0; nt<4; nt++){
            acc[mt][nt] = __builtin_amdgcn_mfma_f32_16x16x32_f16(af[mt][0], bf[nt][0], acc[mt][nt], 0,0,0);
            acc[mt][nt] = __builtin_amdgcn_mfma_f32_16x16x32_f16(af[mt][1], bf[nt][1], acc[mt][nt], 0,0,0);
          }
        __syncthreads();
    }

    float ssc = b2f(scu[1+2*proj]) * b2f(scu[2+2*proj]);
    float qs  = b2f((proj==0)? scu[7] : (proj==1)? scu[8] : scu[11]);
    #pragma unroll
    for (int mt=0; mt<4; mt++){
      #pragma unroll
      for (int nt=0; nt<4; nt++){
        int n = n0 + wn*64 + nt*16 + l15;        // C/D col = lane&15 (verified)
        int nloc = n & 511;
        int h = nloc>>6, d = nloc&63;
        #pragma unroll
        for (int r=0;r<4;r++){
          int m = m0 + wm*64 + mt*16 + quad*4 + r;   // C/D row = quad*4+reg (verified)
          int b = m>>11, s = m&2047;
          int bh = b*8 + h;
          float val = acc[mt][nt][r] * ssc;          // exact integer * scale
          float qv = rintf(clampf(val/qs, -128.f, 127.f));
          if (proj==0)      q16 [(bh*2048 + s)*64 + d] = (_Float16)qv;
          else if (proj==1) k16 [(bh*2048 + s)*64 + d] = (_Float16)qv;
          else              vt16[(bh*64 + d)*2048 + s] = (_Float16)qv;   // transposed
        }
      }
    }
}

// ---------------------------------------------------------------------------
// Fused attention: block = (16 q-rows, bh). Wave w owns t in [w*512,(w+1)*512).
// Scores kept in registers (f32), exact softmax with cross-wave reduce, P
// quantized (sc9 then sc10), staged through barrier-protected LDS into
// A-fragment layout, PV via f16 MFMA, cross-wave reduce, quantize with sc12.
// __launch_bounds__(256,2): 2 blocks/CU -> 256-VGPR budget.
// R4 lesson: the PV `ch` loop MUST be fully unrolled — a runtime index into
// c[32] forces the whole score array to scratch (1.05 GB of spill traffic).
__global__ __launch_bounds__(256, 2) void k_attn(
    const _Float16* __restrict__ q16, const _Float16* __restrict__ k16,
    const _Float16* __restrict__ vt16, _Float16* __restrict__ o16,
    const unsigned short* __restrict__ scu)
{
    __shared__ __align__(16) _Float16 p16[4][16][64];  // per-wave P staging
    __shared__ float red[4][16][64];                   // cross-wave PV reduce
    __shared__ float mred[4][16];
    __shared__ float lred[4][16];
    int tid = threadIdx.x;
    int w = tid>>6, lane = tid&63, l15 = lane&15, quad = lane>>4;
    int bh = blockIdx.y;
    int q0 = blockIdx.x * 16;
    float s9 = b2f(scu[9]), s10 = b2f(scu[10]);
    float alpha = b2f(scu[7]) * b2f(scu[8]) * 0.125f;    // DH^-0.5 = 0.125

    f32x4 z = {0.f,0.f,0.f,0.f};
    const _Float16* qr = q16 + (bh*2048 + q0 + l15)*64;
    half8 aq0 = *(const half8*)(qr + quad*8);
    half8 aq1 = *(const half8*)(qr + 32 + quad*8);

    // QK^T over this wave's 512-wide t range: 32 tiles of 16 t, K=64 in 2 subs
    f32x4 c[32];
    #pragma unroll
    for (int tt=0; tt<32; tt++){
        const _Float16* kr = k16 + (bh*2048 + w*512 + tt*16 + l15)*64;
        half8 bk0 = *(const half8*)(kr + quad*8);
        half8 bk1 = *(const half8*)(kr + 32 + quad*8);
        f32x4 s = __builtin_amdgcn_mfma_f32_16x16x32_f16(aq0, bk0, z, 0,0,0);
        c[tt]   = __builtin_amdgcn_mfma_f32_16x16x32_f16(aq1, bk1, s, 0,0,0);
    }

    // row max over t (cols l15 within quad, tiles, then waves)
    float mr[4] = {-3.4e38f, -3.4e38f, -3.4e38f, -3.4e38f};
    #pragma unroll
    for (int tt=0; tt<32; tt++)
      #pragma unroll
      for (int r=0;r<4;r++)
        mr[r] = fmaxf(mr[r], c[tt][r] * alpha);
    #pragma unroll
    for (int r=0;r<4;r++){
        #pragma unroll
        for (int d=1; d<16; d<<=1)
            mr[r] = fmaxf(mr[r], __shfl_xor(mr[r], d, 64));
    }
    if (l15 == 0){
        #pragma unroll
        for (int r=0;r<4;r++) mred[w][quad*4+r] = mr[r];
    }
    __syncthreads();
    float mm[4];
    #pragma unroll
    for (int r=0;r<4;r++){
        int row = quad*4+r;
        mm[r] = fmaxf(fmaxf(mred[0][row], mred[1][row]), fmaxf(mred[2][row], mred[3][row]));
    }
    // exp + row sum; cache e in the score registers
    float ls[4] = {0.f,0.f,0.f,0.f};
    #pragma unroll
    for (int tt=0; tt<32; tt++)
      #pragma unroll
      for (int r=0;r<4;r++){
        float e = expf(c[tt][r]*alpha - mm[r]);
        ls[r] += e;
        c[tt][r] = e;
      }
    #pragma unroll
    for (int r=0;r<4;r++){
        #pragma unroll
        for (int d=1; d<16; d<<=1)
            ls[r] += __shfl_xor(ls[r], d, 64);
    }
    if (l15 == 0){
        #pragma unroll
        for (int r=0;r<4;r++) lred[w][quad*4+r] = ls[r];
    }
    __syncthreads();
    float inv[4];
    #pragma unroll
    for (int r=0;r<4;r++){
        int row = quad*4+r;
        inv[r] = 1.0f / (lred[0][row] + lred[1][row] + lred[2][row] + lred[3][row]);
    }

    // P·V over this wave's t range, 64-t chunks, barrier-protected LDS transform.
    // FULLY UNROLLED so every c[] index is a compile-time constant (else scratch).
    f32x4 oacc[4];
    #pragma unroll
    for (int dt=0; dt<4; dt++) oacc[dt] = z;
    #pragma unroll
    for (int ch=0; ch<8; ch++){
        #pragma unroll
        for (int j=0;j<4;j++){
            int tt = ch*4 + j;
            #pragma unroll
            for (int r=0;r<4;r++){
                float p  = c[tt][r] * inv[r];
                float p1 = rintf(clampf(p/s9, 0.f, 255.f)) * s9;   // fq(softmax, s9, 0, 255)
                float a  = rintf(clampf(p1/s10, -128.f, 127.f));   // fq(., s10)
                p16[w][quad*4+r][j*16+l15] = (_Float16)a;          // [qrow][tloc]
            }
        }
        __syncthreads();
        half8 ap0 = *(const half8*)(&p16[w][l15][quad*8]);
        half8 ap1 = *(const half8*)(&p16[w][l15][32+quad*8]);
        #pragma unroll
        for (int dt=0; dt<4; dt++){
            const _Float16* vr = vt16 + (bh*64 + dt*16 + l15)*2048 + w*512 + ch*64;
            half8 bv0 = *(const half8*)(vr + quad*8);
            half8 bv1 = *(const half8*)(vr + 32 + quad*8);
            oacc[dt] = __builtin_amdgcn_mfma_f32_16x16x32_f16(ap0, bv0, oacc[dt], 0,0,0);
            oacc[dt] = __builtin_amdgcn_mfma_f32_16x16x32_f16(ap1, bv1, oacc[dt], 0,0,0);
        }
        __syncthreads();
    }

    // cross-wave reduce (waves covered disjoint t ranges; sums are exact ints)
    #pragma unroll
    for (int dt=0; dt<4; dt++)
      #pragma unroll
      for (int r=0;r<4;r++)
        red[w][quad*4+r][dt*16+l15] = oacc[dt][r];
    __syncthreads();
    float s1011 = b2f(scu[10]) * b2f(scu[11]);
    float s12   = b2f(scu[12]);
    int e0 = tid*4;
    int row = e0>>6, col0 = e0&63;
    int b = bh>>3, h = bh&7;
    _Float16 ov[4];
    #pragma unroll
    for (int i=0;i<4;i++){
        int col = col0 + i;
        float sum = red[0][row][col] + red[1][row][col] + red[2][row][col] + red[3][row][col];
        float o = sum * s1011;
        ov[i] = (_Float16)rintf(clampf(o/s12, -128.f, 127.f));
    }
    _Float16* op = o16 + (b*2048 + q0 + row)*512 + h*64 + col0;
    op[0]=ov[0]; op[1]=ov[1]; op[2]=ov[2]; op[3]=ov[3];
}

// ---------------------------------------------------------------------------
// Output projection: M=8192, N=512, K=512, + bias, bf16 out.
__global__ __launch_bounds__(256) void k_gemm_out(
    const _Float16* __restrict__ o16, const _Float16* __restrict__ wo16,
    const unsigned short* __restrict__ bo, unsigned short* __restrict__ out,
    const unsigned short* __restrict__ scu)
{
    __shared__ __align__(16) _Float16 At[128][64];
    __shared__ __align__(16) _Float16 Bt[128][64];
    int tid = threadIdx.x;
    int m0 = blockIdx.x*128, n0 = blockIdx.y*128;
    int w = tid>>6, lane = tid&63, l15 = lane&15, quad = lane>>4;
    int wm = w>>1, wn = w&1;
    f32x4 z = {0.f,0.f,0.f,0.f};
    f32x4 acc[4][4];
    #pragma unroll
    for (int i=0;i<4;i++)
      #pragma unroll
      for (int j=0;j<4;j++) acc[i][j] = z;

    for (int k0=0; k0<512; k0+=64){
        #pragma unroll
        for (int it=0; it<4; it++){
            int idx = it*256 + tid;
            int row = idx>>3, col = (idx&7)*8;
            *(half8*)(&At[row][col]) = *(const half8*)(o16  + (m0+row)*512 + k0 + col);
            *(half8*)(&Bt[row][col]) = *(const half8*)(wo16 + (n0+row)*512 + k0 + col);
        }
        __syncthreads();
        half8 af[4][2], bf[4][2];
        #pragma unroll
        for (int mt=0; mt<4; mt++){
            af[mt][0] = *(const half8*)(&At[wm*64+mt*16+l15][quad*8]);
            af[mt][1] = *(const half8*)(&At[wm*64+mt*16+l15][32+quad*8]);
        }
        #pragma unroll
        for (int nt=0; nt<4; nt++){
            bf[nt][0] = *(const half8*)(&Bt[wn*64+nt*16+l15][quad*8]);
            bf[nt][1] = *(const half8*)(&Bt[wn*64+nt*16+l15][32+quad*8]);
        }
        #pragma unroll
        for (int mt=0; mt<4; mt++)
          #pragma unroll
          for (int nt=0; nt<4; nt++){
            acc[mt][nt] = __builtin_amdgcn_mfma_f32_16x16x32_f16(af[mt][0], bf[nt][0], acc[mt][nt], 0,0,0);
            acc[mt][nt] = __builtin_amdgcn_mfma_f32_16x16x32_f16(af[mt][1], bf[nt][1], acc[mt][nt], 0,0,0);
          }
        __syncthreads();
    }

    float ssc = b2f(scu[12]) * b2f(scu[13]);
    #pragma unroll
    for (int mt=0; mt<4; mt++){
      #pragma unroll
      for (int nt=0; nt<4; nt++){
        int n = n0 + wn*64 + nt*16 + l15;
        float bn = b2f(bo[n]);
        #pragma unroll
        for (int r=0;r<4;r++){
          int m = m0 + wm*64 + mt*16 + quad*4 + r;
          out[m*512 + n] = f2b(acc[mt][nt][r]*ssc + bn);
        }
      }
    }
}

// ---------------------------------------------------------------------------
extern "C" void kernel_launch(void* const* d_in, const int* in_sizes, int n_in,
                              void* d_out, int out_size, void* d_ws, size_t ws_size,
                              hipStream_t stream)
{
    const unsigned short* hs = (const unsigned short*)d_in[0];
    const unsigned short* Wq = (const unsigned short*)d_in[1];
    const unsigned short* Wk = (const unsigned short*)d_in[2];
    const unsigned short* Wv = (const unsigned short*)d_in[3];
    const unsigned short* Wo = (const unsigned short*)d_in[4];
    const unsigned short* bo = (const unsigned short*)d_in[5];
    const unsigned short* sc = (const unsigned short*)d_in[6];
    unsigned short* out = (unsigned short*)d_out;

    _Float16* wsh   = (_Float16*)d_ws;
    _Float16* w_all = wsh + EW_WALL;
    _Float16* wo16  = wsh + EW_WO;
    _Float16* a_q   = wsh + EW_AQ;
    _Float16* a_k   = wsh + EW_AK;
    _Float16* a_v   = wsh + EW_AV;
    _Float16* q16   = wsh + EW_Q;
    _Float16* k16   = wsh + EW_K;
    _Float16* vt16  = wsh + EW_VT;
    _Float16* o16   = wsh + EW_O;

    k_quant_w<<<512,  256, 0, stream>>>(Wq, Wk, Wv, Wo, w_all, wo16, sc);
    k_quant_a<<<2048, 256, 0, stream>>>(hs, a_q, a_k, a_v, sc);
    k_gemm_qkv<<<dim3(64,12), 256, 0, stream>>>(a_q, a_k, a_v, w_all, q16, k16, vt16, sc);
    k_attn<<<dim3(128,32), 256, 0, stream>>>(q16, k16, vt16, o16, sc);
    k_gemm_out<<<dim3(64,4), 256, 0, stream>>>(o16, wo16, bo, out, sc);
}

// Round 6
// 397.544 us; speedup vs baseline: 1.8450x; 1.1483x over previous
//
#include <hip/hip_runtime.h>

typedef _Float16 half8  __attribute__((ext_vector_type(8)));
typedef float    f32x4  __attribute__((ext_vector_type(4)));
typedef unsigned short ushort8 __attribute__((ext_vector_type(8)));

__device__ __forceinline__ float clampf(float v, float lo, float hi){
    return fminf(fmaxf(v, lo), hi);
}
__device__ __forceinline__ float b2f(unsigned short u){
    unsigned int x = ((unsigned int)u) << 16;
    return __builtin_bit_cast(float, x);
}
__device__ __forceinline__ unsigned short f2b(float f){
    unsigned int u = __builtin_bit_cast(unsigned int, f);
    u += 0x7FFFu + ((u >> 16) & 1u);       // round-to-nearest-even
    return (unsigned short)(u >> 16);
}

// ---------------------------------------------------------------------------
// ws layout in _Float16 ELEMENT offsets (all tensors stored as integer-valued f16)
#define EW_WALL 0u                       // [1536][512] packed Wq/Wk/Wv rows
#define EW_WO   786432u                  // [512][512]
#define EW_AQ   1048576u                 // [8192][512] act for q-proj
#define EW_AK   (EW_AQ + 4194304u)
#define EW_AV   (EW_AK + 4194304u)
#define EW_Q    (EW_AV + 4194304u)       // [bh=32][s=2048][d=64]
#define EW_K    (EW_Q  + 4194304u)       // [bh][s][d]
#define EW_VT   (EW_K  + 4194304u)       // [bh][d=64][s=2048]  (V transposed)
#define EW_O    (EW_VT + 4194304u)       // [8192][512]
// total = 30,408,704 elements = 60,817,408 bytes

// ---------------------------------------------------------------------------
__global__ __launch_bounds__(256) void k_quant_w(
    const unsigned short* __restrict__ Wq, const unsigned short* __restrict__ Wk,
    const unsigned short* __restrict__ Wv, const unsigned short* __restrict__ Wo,
    _Float16* __restrict__ w_all, _Float16* __restrict__ wo16,
    const unsigned short* __restrict__ scu)
{
    int gid  = blockIdx.x * 256 + threadIdx.x;   // 131072 threads, 8 elems each
    int idx8 = gid * 8;
    int which = idx8 >> 18;                      // 262144 elems per matrix
    int rem   = idx8 & 262143;
    const unsigned short* W = (which==0)? Wq : (which==1)? Wk : (which==2)? Wv : Wo;
    float sw = b2f((which<3) ? scu[2 + 2*which] : scu[13]);
    ushort8 w = *(const ushort8*)(W + rem);
    half8 o;
    #pragma unroll
    for (int j=0;j<8;j++)
        o[j] = (_Float16)rintf(clampf(b2f(w[j])/sw, -128.f, 127.f));
    _Float16* dst = (which<3) ? (w_all + which*262144 + rem) : (wo16 + rem);
    *(half8*)dst = o;
}

// ---------------------------------------------------------------------------
__global__ __launch_bounds__(256) void k_quant_a(
    const unsigned short* __restrict__ hs,
    _Float16* __restrict__ aq, _Float16* __restrict__ ak, _Float16* __restrict__ av,
    const unsigned short* __restrict__ scu)
{
    int gid = blockIdx.x * 256 + threadIdx.x;    // 524288 threads, 8 elems each
    int i8 = gid * 8;
    float s0 = b2f(scu[0]), s1 = b2f(scu[1]), s3 = b2f(scu[3]), s5 = b2f(scu[5]);
    ushort8 h = *(const ushort8*)(hs + i8);
    half8 q, k, v;
    #pragma unroll
    for (int j=0;j<8;j++){
        float h1 = rintf(clampf(b2f(h[j])/s0, -128.f, 127.f)) * s0;  // fq(hs, s0)
        q[j] = (_Float16)rintf(clampf(h1/s1, -128.f, 127.f));
        k[j] = (_Float16)rintf(clampf(h1/s3, -128.f, 127.f));
        v[j] = (_Float16)rintf(clampf(h1/s5, -128.f, 127.f));
    }
    *(half8*)(aq+i8) = q;
    *(half8*)(ak+i8) = k;
    *(half8*)(av+i8) = v;
}

// ---------------------------------------------------------------------------
// QKV projection: M=8192, N=1536 (3 projections x 512), K=512. 128x128 tiles,
// 4 waves each doing 64x64 via verified mfma_f32_16x16x32_f16 (exact int math).
__global__ __launch_bounds__(256) void k_gemm_qkv(
    const _Float16* __restrict__ aq, const _Float16* __restrict__ ak,
    const _Float16* __restrict__ av, const _Float16* __restrict__ w_all,
    _Float16* __restrict__ q16, _Float16* __restrict__ k16, _Float16* __restrict__ vt16,
    const unsigned short* __restrict__ scu)
{
    __shared__ __align__(16) _Float16 At[128][64];
    __shared__ __align__(16) _Float16 Bt[128][64];
    int tid = threadIdx.x;
    int m0 = blockIdx.x*128, n0 = blockIdx.y*128;
    int proj = blockIdx.y >> 2;                  // 4 n-blocks per projection
    const _Float16* Ag = (proj==0)? aq : (proj==1)? ak : av;
    int w = tid>>6, lane = tid&63, l15 = lane&15, quad = lane>>4;
    int wm = w>>1, wn = w&1;
    f32x4 z = {0.f,0.f,0.f,0.f};
    f32x4 acc[4][4];
    #pragma unroll
    for (int i=0;i<4;i++)
      #pragma unroll
      for (int j=0;j<4;j++) acc[i][j] = z;

    for (int k0=0; k0<512; k0+=64){
        #pragma unroll
        for (int it=0; it<4; it++){
            int idx = it*256 + tid;              // 0..1023
            int row = idx>>3, col = (idx&7)*8;
            *(half8*)(&At[row][col]) = *(const half8*)(Ag    + (m0+row)*512 + k0 + col);
            *(half8*)(&Bt[row][col]) = *(const half8*)(w_all + (n0+row)*512 + k0 + col);
        }
        __syncthreads();
        half8 af[4][2], bf[4][2];
        #pragma unroll
        for (int mt=0; mt<4; mt++){
            af[mt][0] = *(const half8*)(&At[wm*64+mt*16+l15][quad*8]);
            af[mt][1] = *(const half8*)(&At[wm*64+mt*16+l15][32+quad*8]);
        }
        #pragma unroll
        for (int nt=0; nt<4; nt++){
            bf[nt][0] = *(const half8*)(&Bt[wn*64+nt*16+l15][quad*8]);
            bf[nt][1] = *(const half8*)(&Bt[wn*64+nt*16+l15][32+quad*8]);
        }
        #pragma unroll
        for (int mt=0; mt<4; mt++)
          #pragma unroll
          for (int nt=0; nt<4; nt++){
            acc[mt][nt] = __builtin_amdgcn_mfma_f32_16x16x32_f16(af[mt][0], bf[nt][0], acc[mt][nt], 0,0,0);
            acc[mt][nt] = __builtin_amdgcn_mfma_f32_16x16x32_f16(af[mt][1], bf[nt][1], acc[mt][nt], 0,0,0);
          }
        __syncthreads();
    }

    float ssc = b2f(scu[1+2*proj]) * b2f(scu[2+2*proj]);
    float qs  = b2f((proj==0)? scu[7] : (proj==1)? scu[8] : scu[11]);
    #pragma unroll
    for (int mt=0; mt<4; mt++){
      #pragma unroll
      for (int nt=0; nt<4; nt++){
        int n = n0 + wn*64 + nt*16 + l15;        // C/D col = lane&15 (verified)
        int nloc = n & 511;
        int h = nloc>>6, d = nloc&63;
        #pragma unroll
        for (int r=0;r<4;r++){
          int m = m0 + wm*64 + mt*16 + quad*4 + r;   // C/D row = quad*4+reg (verified)
          int b = m>>11, s = m&2047;
          int bh = b*8 + h;
          float val = acc[mt][nt][r] * ssc;          // exact integer * scale
          float qv = rintf(clampf(val/qs, -128.f, 127.f));
          if (proj==0)      q16 [(bh*2048 + s)*64 + d] = (_Float16)qv;
          else if (proj==1) k16 [(bh*2048 + s)*64 + d] = (_Float16)qv;
          else              vt16[(bh*64 + d)*2048 + s] = (_Float16)qv;   // transposed
        }
      }
    }
}

// ---------------------------------------------------------------------------
// Fused attention: block = (16 q-rows, bh). Wave w owns t in [w*512,(w+1)*512).
// Scores kept in registers (f32), exact softmax with cross-wave reduce, P
// quantized (sc9 then sc10), staged wave-synchronously through LDS into
// A-fragment layout (NO barrier needed: p16[w] is written and read only by
// wave w — lgkmcnt ordering suffices; R5's 16 per-chunk barriers were the
// dominant stall), PV via f16 MFMA, cross-wave reduce, quantize with sc12.
// __launch_bounds__(256,2): 2 blocks/CU -> 256-reg budget (c[32]=128 AGPRs).
// R4 lesson: PV loop fully unrolled — runtime index into c[32] => scratch.
__global__ __launch_bounds__(256, 2) void k_attn(
    const _Float16* __restrict__ q16, const _Float16* __restrict__ k16,
    const _Float16* __restrict__ vt16, _Float16* __restrict__ o16,
    const unsigned short* __restrict__ scu)
{
    __shared__ __align__(16) _Float16 p16[4][16][72];  // per-wave P staging (+8 pad: 4-way->2-way banks)
    __shared__ float red[4][16][64];                   // cross-wave PV reduce
    __shared__ float mred[4][16];
    __shared__ float lred[4][16];
    int tid = threadIdx.x;
    int w = tid>>6, lane = tid&63, l15 = lane&15, quad = lane>>4;
    int bh = blockIdx.y;
    int q0 = blockIdx.x * 16;
    float s9 = b2f(scu[9]), s10 = b2f(scu[10]);
    float alpha = b2f(scu[7]) * b2f(scu[8]) * 0.125f;    // DH^-0.5 = 0.125
    float al2 = alpha * 1.44269504088896341f;            // alpha * log2(e)

    f32x4 z = {0.f,0.f,0.f,0.f};
    const _Float16* qr = q16 + (bh*2048 + q0 + l15)*64;
    half8 aq0 = *(const half8*)(qr + quad*8);
    half8 aq1 = *(const half8*)(qr + 32 + quad*8);

    // QK^T over this wave's 512-wide t range: 32 tiles of 16 t, K=64 in 2 subs
    f32x4 c[32];
    #pragma unroll
    for (int tt=0; tt<32; tt++){
        const _Float16* kr = k16 + (bh*2048 + w*512 + tt*16 + l15)*64;
        half8 bk0 = *(const half8*)(kr + quad*8);
        half8 bk1 = *(const half8*)(kr + 32 + quad*8);
        f32x4 s = __builtin_amdgcn_mfma_f32_16x16x32_f16(aq0, bk0, z, 0,0,0);
        c[tt]   = __builtin_amdgcn_mfma_f32_16x16x32_f16(aq1, bk1, s, 0,0,0);
    }

    // row max over RAW integer scores (alpha>0 so max commutes with scaling)
    float mr[4] = {-3.4e38f, -3.4e38f, -3.4e38f, -3.4e38f};
    #pragma unroll
    for (int tt=0; tt<32; tt++)
      #pragma unroll
      for (int r=0;r<4;r++)
        mr[r] = fmaxf(mr[r], c[tt][r]);
    #pragma unroll
    for (int r=0;r<4;r++){
        #pragma unroll
        for (int d=1; d<16; d<<=1)
            mr[r] = fmaxf(mr[r], __shfl_xor(mr[r], d, 64));
    }
    if (l15 == 0){
        #pragma unroll
        for (int r=0;r<4;r++) mred[w][quad*4+r] = mr[r];
    }
    __syncthreads();
    float mm2[4];
    #pragma unroll
    for (int r=0;r<4;r++){
        int row = quad*4+r;
        float m = fmaxf(fmaxf(mred[0][row], mred[1][row]), fmaxf(mred[2][row], mred[3][row]));
        mm2[r] = m * al2;                      // in log2-units
    }
    // exp2 + row sum; cache e in the score registers (fma + v_exp per element)
    float ls[4] = {0.f,0.f,0.f,0.f};
    #pragma unroll
    for (int tt=0; tt<32; tt++)
      #pragma unroll
      for (int r=0;r<4;r++){
        float e = exp2f(c[tt][r]*al2 - mm2[r]);
        ls[r] += e;
        c[tt][r] = e;
      }
    #pragma unroll
    for (int r=0;r<4;r++){
        #pragma unroll
        for (int d=1; d<16; d<<=1)
            ls[r] += __shfl_xor(ls[r], d, 64);
    }
    if (l15 == 0){
        #pragma unroll
        for (int r=0;r<4;r++) lred[w][quad*4+r] = ls[r];
    }
    __syncthreads();
    // q9[r] = inv_rowsum / s9 ; r910 = s9/s10 (generic runtime scales)
    float inv_s9 = 1.0f / s9;
    float r910   = s9 / s10;
    float q9[4];
    #pragma unroll
    for (int r=0;r<4;r++){
        int row = quad*4+r;
        float tot = lred[0][row] + lred[1][row] + lred[2][row] + lred[3][row];
        q9[r] = inv_s9 / tot;
    }

    // P·V over this wave's t range, 64-t chunks, wave-synchronous LDS transform
    // (no barriers: intra-wave producer/consumer, lgkmcnt orders it).
    // fq chain per element (6 VALU): p1i = rint(min(e*q9,255)) ; a = rint(min(p1i*r910,127))
    // (lower clamps dead: e,q9,p1i,r910 all >= 0)
    f32x4 oacc[4];
    #pragma unroll
    for (int dt=0; dt<4; dt++) oacc[dt] = z;
    #pragma unroll
    for (int ch=0; ch<8; ch++){
        #pragma unroll
        for (int j=0;j<4;j++){
            int tt = ch*4 + j;
            #pragma unroll
            for (int r=0;r<4;r++){
                float p1i = rintf(fminf(c[tt][r]*q9[r], 255.f));   // fq(softmax,s9,0,255) int
                float a   = rintf(fminf(p1i*r910, 127.f));         // fq(.,s10) int
                p16[w][quad*4+r][j*16+l15] = (_Float16)a;          // [qrow][tloc]
            }
        }
        half8 ap0 = *(const half8*)(&p16[w][l15][quad*8]);
        half8 ap1 = *(const half8*)(&p16[w][l15][32+quad*8]);
        #pragma unroll
        for (int dt=0; dt<4; dt++){
            const _Float16* vr = vt16 + (bh*64 + dt*16 + l15)*2048 + w*512 + ch*64;
            half8 bv0 = *(const half8*)(vr + quad*8);
            half8 bv1 = *(const half8*)(vr + 32 + quad*8);
            oacc[dt] = __builtin_amdgcn_mfma_f32_16x16x32_f16(ap0, bv0, oacc[dt], 0,0,0);
            oacc[dt] = __builtin_amdgcn_mfma_f32_16x16x32_f16(ap1, bv1, oacc[dt], 0,0,0);
        }
    }

    // cross-wave reduce (waves covered disjoint t ranges; sums are exact ints)
    #pragma unroll
    for (int dt=0; dt<4; dt++)
      #pragma unroll
      for (int r=0;r<4;r++)
        red[w][quad*4+r][dt*16+l15] = oacc[dt][r];
    __syncthreads();
    float s1011 = b2f(scu[10]) * b2f(scu[11]);
    float s12   = b2f(scu[12]);
    int e0 = tid*4;
    int row = e0>>6, col0 = e0&63;
    int b = bh>>3, h = bh&7;
    _Float16 ov[4];
    #pragma unroll
    for (int i=0;i<4;i++){
        int col = col0 + i;
        float sum = red[0][row][col] + red[1][row][col] + red[2][row][col] + red[3][row][col];
        float o = sum * s1011;
        ov[i] = (_Float16)rintf(clampf(o/s12, -128.f, 127.f));
    }
    _Float16* op = o16 + (b*2048 + q0 + row)*512 + h*64 + col0;
    op[0]=ov[0]; op[1]=ov[1]; op[2]=ov[2]; op[3]=ov[3];
}

// ---------------------------------------------------------------------------
// Output projection: M=8192, N=512, K=512, + bias, bf16 out.
__global__ __launch_bounds__(256) void k_gemm_out(
    const _Float16* __restrict__ o16, const _Float16* __restrict__ wo16,
    const unsigned short* __restrict__ bo, unsigned short* __restrict__ out,
    const unsigned short* __restrict__ scu)
{
    __shared__ __align__(16) _Float16 At[128][64];
    __shared__ __align__(16) _Float16 Bt[128][64];
    int tid = threadIdx.x;
    int m0 = blockIdx.x*128, n0 = blockIdx.y*128;
    int w = tid>>6, lane = tid&63, l15 = lane&15, quad = lane>>4;
    int wm = w>>1, wn = w&1;
    f32x4 z = {0.f,0.f,0.f,0.f};
    f32x4 acc[4][4];
    #pragma unroll
    for (int i=0;i<4;i++)
      #pragma unroll
      for (int j=0;j<4;j++) acc[i][j] = z;

    for (int k0=0; k0<512; k0+=64){
        #pragma unroll
        for (int it=0; it<4; it++){
            int idx = it*256 + tid;
            int row = idx>>3, col = (idx&7)*8;
            *(half8*)(&At[row][col]) = *(const half8*)(o16  + (m0+row)*512 + k0 + col);
            *(half8*)(&Bt[row][col]) = *(const half8*)(wo16 + (n0+row)*512 + k0 + col);
        }
        __syncthreads();
        half8 af[4][2], bf[4][2];
        #pragma unroll
        for (int mt=0; mt<4; mt++){
            af[mt][0] = *(const half8*)(&At[wm*64+mt*16+l15][quad*8]);
            af[mt][1] = *(const half8*)(&At[wm*64+mt*16+l15][32+quad*8]);
        }
        #pragma unroll
        for (int nt=0; nt<4; nt++){
            bf[nt][0] = *(const half8*)(&Bt[wn*64+nt*16+l15][quad*8]);
            bf[nt][1] = *(const half8*)(&Bt[wn*64+nt*16+l15][32+quad*8]);
        }
        #pragma unroll
        for (int mt=0; mt<4; mt++)
          #pragma unroll
          for (int nt=0; nt<4; nt++){
            acc[mt][nt] = __builtin_amdgcn_mfma_f32_16x16x32_f16(af[mt][0], bf[nt][0], acc[mt][nt], 0,0,0);
            acc[mt][nt] = __builtin_amdgcn_mfma_f32_16x16x32_f16(af[mt][1], bf[nt][1], acc[mt][nt], 0,0,0);
          }
        __syncthreads();
    }

    float ssc = b2f(scu[12]) * b2f(scu[13]);
    #pragma unroll
    for (int mt=0; mt<4; mt++){
      #pragma unroll
      for (int nt=0; nt<4; nt++){
        int n = n0 + wn*64 + nt*16 + l15;
        float bn = b2f(bo[n]);
        #pragma unroll
        for (int r=0;r<4;r++){
          int m = m0 + wm*64 + mt*16 + quad*4 + r;
          out[m*512 + n] = f2b(acc[mt][nt][r]*ssc + bn);
        }
      }
    }
}

// ---------------------------------------------------------------------------
extern "C" void kernel_launch(void* const* d_in, const int* in_sizes, int n_in,
                              void* d_out, int out_size, void* d_ws, size_t ws_size,
                              hipStream_t stream)
{
    const unsigned short* hs = (const unsigned short*)d_in[0];
    const unsigned short* Wq = (const unsigned short*)d_in[1];
    const unsigned short* Wk = (const unsigned short*)d_in[2];
    const unsigned short* Wv = (const unsigned short*)d_in[3];
    const unsigned short* Wo = (const unsigned short*)d_in[4];
    const unsigned short* bo = (const unsigned short*)d_in[5];
    const unsigned short* sc = (const unsigned short*)d_in[6];
    unsigned short* out = (unsigned short*)d_out;

    _Float16* wsh   = (_Float16*)d_ws;
    _Float16* w_all = wsh + EW_WALL;
    _Float16* wo16  = wsh + EW_WO;
    _Float16* a_q   = wsh + EW_AQ;
    _Float16* a_k   = wsh + EW_AK;
    _Float16* a_v   = wsh + EW_AV;
    _Float16* q16   = wsh + EW_Q;
    _Float16* k16   = wsh + EW_K;
    _Float16* vt16  = wsh + EW_VT;
    _Float16* o16   = wsh + EW_O;

    k_quant_w<<<512,  256, 0, stream>>>(Wq, Wk, Wv, Wo, w_all, wo16, sc);
    k_quant_a<<<2048, 256, 0, stream>>>(hs, a_q, a_k, a_v, sc);
    k_gemm_qkv<<<dim3(64,12), 256, 0, stream>>>(a_q, a_k, a_v, w_all, q16, k16, vt16, sc);
    k_attn<<<dim3(128,32), 256, 0, stream>>>(q16, k16, vt16, o16, sc);
    k_gemm_out<<<dim3(64,4), 256, 0, stream>>>(o16, wo16, bo, out, sc);
}